// Round 10
// baseline (1734.069 us; speedup 1.0000x reference)
//
#include <hip/hip_runtime.h>
#include <hip/hip_bf16.h>

#define HID 256
#define FIN 128
#define NGRAPH 64
#define NEG 0.2f

__device__ __forceinline__ float lrelu(float v) { return v >= 0.f ? v : NEG * v; }

// deg = 1.0 (self-loop weight), pooled = 0
__global__ void k_init(float* __restrict__ deg, float* __restrict__ pooled, int N) {
    int i = blockIdx.x * 256 + threadIdx.x;
    if (i < N) deg[i] = 1.0f;
    if (i < NGRAPH * HID) pooled[i] = 0.0f;
}

// deg[col[e]] += ew[e]   (col = second row of edge_index)
__global__ void k_deg(const int* __restrict__ col, const float* __restrict__ ew,
                      float* __restrict__ deg, int E) {
    int e = blockIdx.x * 256 + threadIdx.x;
    if (e < E) atomicAdd(&deg[col[e]], ew[e]);
}

// in place deg -> rsqrt(deg)
__global__ void k_dinv(float* __restrict__ deg, int N) {
    int i = blockIdx.x * 256 + threadIdx.x;
    if (i < N) {
        float d = deg[i];
        deg[i] = d > 0.f ? rsqrtf(d) : 0.f;
    }
}

// xagg[n] = dinv[n]^2 * x[n]  (self-loop term; zero-bases xagg). float4 over N*32.
__global__ void k_selfx(const float* __restrict__ x, const float* __restrict__ dinv,
                        float* __restrict__ xagg, int N) {
    int i = blockIdx.x * 256 + threadIdx.x;
    if (i < N * (FIN / 4)) {
        int n = i >> 5;
        float s = dinv[n]; s = s * s;
        float4 v = ((const float4*)x)[i];
        v.x *= s; v.y *= s; v.z *= s; v.w *= s;
        ((float4*)xagg)[i] = v;
    }
}

// 8 edges per 256-thread block; 32 lanes x float4 per edge.
// xagg[col[e]] += dinv[row]*ew*dinv[col] * x[row[e]]
__global__ __launch_bounds__(256) void k_scatx(const int* __restrict__ row,
        const int* __restrict__ col, const float* __restrict__ ew,
        const float* __restrict__ dinv, const float* __restrict__ x,
        float* __restrict__ xagg, int E) {
    int e = blockIdx.x * 8 + (threadIdx.x >> 5);
    int l = threadIdx.x & 31;
    if (e >= E) return;
    int r = row[e], c = col[e];
    float w = dinv[r] * ew[e] * dinv[c];
    const float4 v = ((const float4*)(x + (size_t)r * FIN))[l];
    float* dst = xagg + (size_t)c * FIN + l * 4;
    atomicAdd(dst + 0, w * v.x);
    atomicAdd(dst + 1, w * v.y);
    atomicAdd(dst + 2, w * v.z);
    atomicAdd(dst + 3, w * v.w);
}

// starts[g] = lower_bound(batch, g); starts[64] = N
__global__ void k_starts(const int* __restrict__ batch, int* __restrict__ starts, int N) {
    int g = threadIdx.x;
    if (g > NGRAPH) return;
    int lo = 0, hi = N;
    while (lo < hi) {
        int mid = (lo + hi) >> 1;
        if (batch[mid] < g) lo = mid + 1; else hi = mid;
    }
    starts[g] = lo;
}

// one 256-thread block per node: h_j = xagg[n]·W1[:,j] + b1_j;
// pooled[batch[n]][j] += lrelu(h_j)
__global__ void k_gemmpool(const float* __restrict__ xagg, const float* __restrict__ W1,
                           const float* __restrict__ b1, const int* __restrict__ batch,
                           float* __restrict__ pooled, int N) {
    __shared__ float xr[FIN];
    int n = blockIdx.x, j = threadIdx.x;
    if (j < FIN) xr[j] = xagg[(size_t)n * FIN + j];
    __syncthreads();
    float acc = b1[j];
    #pragma unroll 8
    for (int k = 0; k < FIN; ++k) acc += xr[k] * W1[(size_t)k * HID + j];
    atomicAdd(&pooled[batch[n] * HID + j], lrelu(acc));
}

// head: z = [pooled/cnt | emb[label]]; a = lrelu(z@W2+b2); out[g] = a·W3 + b3  (f32!)
__global__ void k_head(const float* __restrict__ pooled, const int* __restrict__ starts,
                       const float* __restrict__ emb, const int* __restrict__ labels,
                       const float* __restrict__ W2, const float* __restrict__ b2,
                       const float* __restrict__ W3, const float* __restrict__ b3,
                       float* __restrict__ out) {
    __shared__ float z[384];
    __shared__ float red[256];
    int g = blockIdx.x, t = threadIdx.x;
    int cnt = starts[g + 1] - starts[g];
    float inv = 1.0f / (float)(cnt < 1 ? 1 : cnt);
    z[t] = pooled[g * HID + t] * inv;
    if (t < 128) z[HID + t] = emb[labels[g] * 128 + t];
    __syncthreads();
    float acc = b2[t];
    for (int k = 0; k < 384; ++k) acc += z[k] * W2[k * HID + t];
    red[t] = lrelu(acc) * W3[t];
    __syncthreads();
    for (int s = 128; s > 0; s >>= 1) {
        if (t < s) red[t] += red[t + s];
        __syncthreads();
    }
    if (t == 0) out[g] = red[0] + b3[0];
}

extern "C" void kernel_launch(void* const* d_in, const int* in_sizes, int n_in,
                              void* d_out, int out_size, void* d_ws, size_t ws_size,
                              hipStream_t stream) {
    (void)n_in; (void)out_size; (void)ws_size;
    const float* x      = (const float*)d_in[0];
    const int*   ei     = (const int*)d_in[1];
    const float* ew     = (const float*)d_in[2];
    const int*   batch  = (const int*)d_in[3];
    const int*   labels = (const int*)d_in[4];
    const float* W1     = (const float*)d_in[5];
    const float* b1     = (const float*)d_in[6];
    const float* emb    = (const float*)d_in[7];
    const float* W2     = (const float*)d_in[8];
    const float* b2     = (const float*)d_in[9];
    const float* W3     = (const float*)d_in[10];
    const float* b3     = (const float*)d_in[11];
    const int N = in_sizes[3];   // 50000
    const int E = in_sizes[2];   // 800000
    const int* row = ei;
    const int* col = ei + E;

    float* xagg   = (float*)d_ws;                 // N*128
    float* deg    = xagg + (size_t)N * FIN;       // N (becomes dinv)
    float* pooled = deg + N;                      // 64*256
    int*   starts = (int*)(pooled + NGRAPH * HID);// 65

    k_init<<<(N + 255) / 256, 256, 0, stream>>>(deg, pooled, N);
    k_deg<<<(E + 255) / 256, 256, 0, stream>>>(col, ew, deg, E);
    k_dinv<<<(N + 255) / 256, 256, 0, stream>>>(deg, N);
    k_selfx<<<(N * (FIN / 4) + 255) / 256, 256, 0, stream>>>(x, deg, xagg, N);
    k_scatx<<<(E + 7) / 8, 256, 0, stream>>>(row, col, ew, deg, x, xagg, E);
    k_starts<<<1, 128, 0, stream>>>(batch, starts, N);
    k_gemmpool<<<N, 256, 0, stream>>>(xagg, W1, b1, batch, pooled, N);
    k_head<<<NGRAPH, 256, 0, stream>>>(pooled, starts, emb, labels, W2, b2, W3, b3,
                                       (float*)d_out);
}

// Round 11
// 612.092 us; speedup vs baseline: 2.8330x; 2.8330x over previous
//
#include <hip/hip_runtime.h>

#define HID 256
#define FIN 128
#define NGRAPH 64
#define NEG 0.2f

__device__ __forceinline__ float lrelu(float v) { return v >= 0.f ? v : NEG * v; }

// ---------------- shared kernels (validated in round 10) ----------------

// deg = 1.0 (self-loop weight), cnt = 0, pooled = 0
__global__ void k_init(float* __restrict__ deg, int* __restrict__ cnt,
                       float* __restrict__ pooled, int N) {
    int i = blockIdx.x * 256 + threadIdx.x;
    if (i < N) { deg[i] = 1.0f; cnt[i] = 0; }
    if (i < NGRAPH * HID) pooled[i] = 0.0f;
}

// per edge: weighted degree + incoming-edge count at dest col[e]
__global__ void k_count(const int* __restrict__ col, const float* __restrict__ ew,
                        float* __restrict__ deg, int* __restrict__ cnt, int E) {
    int e = blockIdx.x * 256 + threadIdx.x;
    if (e < E) {
        int c = col[e];
        atomicAdd(&deg[c], ew[e]);
        atomicAdd(&cnt[c], 1);
    }
}

__global__ void k_dinv(float* __restrict__ deg, int N) {
    int i = blockIdx.x * 256 + threadIdx.x;
    if (i < N) {
        float d = deg[i];
        deg[i] = d > 0.f ? rsqrtf(d) : 0.f;
    }
}

// starts[g] = lower_bound(batch, g); starts[64] = N
__global__ void k_starts(const int* __restrict__ batch, int* __restrict__ starts, int N) {
    int g = threadIdx.x;
    if (g > NGRAPH) return;
    int lo = 0, hi = N;
    while (lo < hi) {
        int mid = (lo + hi) >> 1;
        if (batch[mid] < g) lo = mid + 1; else hi = mid;
    }
    starts[g] = lo;
}

// one 256-thread block per node (validated round 10)
__global__ void k_gemmpool(const float* __restrict__ xagg, const float* __restrict__ W1,
                           const float* __restrict__ b1, const int* __restrict__ batch,
                           float* __restrict__ pooled, int N) {
    __shared__ float xr[FIN];
    int n = blockIdx.x, j = threadIdx.x;
    if (j < FIN) xr[j] = xagg[(size_t)n * FIN + j];
    __syncthreads();
    float acc = b1[j];
    #pragma unroll 8
    for (int k = 0; k < FIN; ++k) acc += xr[k] * W1[(size_t)k * HID + j];
    atomicAdd(&pooled[batch[n] * HID + j], lrelu(acc));
}

// head (validated round 10), f32 output
__global__ void k_head(const float* __restrict__ pooled, const int* __restrict__ starts,
                       const float* __restrict__ emb, const int* __restrict__ labels,
                       const float* __restrict__ W2, const float* __restrict__ b2,
                       const float* __restrict__ W3, const float* __restrict__ b3,
                       float* __restrict__ out) {
    __shared__ float z[384];
    __shared__ float red[256];
    int g = blockIdx.x, t = threadIdx.x;
    int cnt = starts[g + 1] - starts[g];
    float inv = 1.0f / (float)(cnt < 1 ? 1 : cnt);
    z[t] = pooled[g * HID + t] * inv;
    if (t < 128) z[HID + t] = emb[labels[g] * 128 + t];
    __syncthreads();
    float acc = b2[t];
    for (int k = 0; k < 384; ++k) acc += z[k] * W2[k * HID + t];
    red[t] = lrelu(acc) * W3[t];
    __syncthreads();
    for (int s = 128; s > 0; s >>= 1) {
        if (t < s) red[t] += red[t + s];
        __syncthreads();
    }
    if (t == 0) out[g] = red[0] + b3[0];
}

// ---------------- CSR build (new) ----------------

// block-local inclusive scan of cnt -> off[i+1]; block sums -> bsum
__global__ void k_scanA(const int* __restrict__ cnt, int* __restrict__ off,
                        int* __restrict__ bsum, int N) {
    __shared__ int buf[256];
    int t = threadIdx.x, i = blockIdx.x * 256 + t;
    buf[t] = (i < N) ? cnt[i] : 0;
    __syncthreads();
    for (int s = 1; s < 256; s <<= 1) {
        int a = (t >= s) ? buf[t - s] : 0;
        __syncthreads();
        buf[t] += a;
        __syncthreads();
    }
    if (i < N) off[i + 1] = buf[t];
    if (t == 255) bsum[blockIdx.x] = buf[255];
}

// single block: inclusive scan of bsum[nb] (nb <= 256)
__global__ void k_scanB(int* __restrict__ bsum, int nb) {
    __shared__ int buf[256];
    int t = threadIdx.x;
    buf[t] = (t < nb) ? bsum[t] : 0;
    __syncthreads();
    for (int s = 1; s < 256; s <<= 1) {
        int a = (t >= s) ? buf[t - s] : 0;
        __syncthreads();
        buf[t] += a;
        __syncthreads();
    }
    if (t < nb) bsum[t] = buf[t];
}

// add block prefix; off[0] = 0
__global__ void k_scanC(int* __restrict__ off, const int* __restrict__ bsum, int N) {
    int i = blockIdx.x * 256 + threadIdx.x;
    if (i < N && blockIdx.x > 0) off[i + 1] += bsum[blockIdx.x - 1];
    if (i == 0) off[0] = 0;
}

// claim slot via atomicSub on cnt (cnt becomes 0 afterwards); store src + weight
__global__ void k_fill(const int* __restrict__ row, const int* __restrict__ col,
                       const float* __restrict__ ew, const float* __restrict__ dinv,
                       const int* __restrict__ off, int* __restrict__ cnt,
                       int* __restrict__ esrc, float* __restrict__ ewgt, int E) {
    int e = blockIdx.x * 256 + threadIdx.x;
    if (e >= E) return;
    int r = row[e], c = col[e];
    int p = atomicSub(&cnt[c], 1) - 1;
    int s = off[c] + p;
    esrc[s] = r;
    ewgt[s] = dinv[r] * ew[e] * dinv[c];
}

// atomic-free pull: 2 nodes per 256-thread block, 128 threads per node.
// xagg[n][k] = dinv[n]^2 * x[n][k] + sum_s ewgt[s] * x[esrc[s]][k]
__global__ __launch_bounds__(256) void k_gather(const int* __restrict__ off,
        const int* __restrict__ esrc, const float* __restrict__ ewgt,
        const float* __restrict__ x, const float* __restrict__ dinv,
        float* __restrict__ xagg, int N) {
    int n = blockIdx.x * 2 + (threadIdx.x >> 7);
    int k = threadIdx.x & 127;
    if (n >= N) return;
    float d = dinv[n];
    float acc = d * d * x[(size_t)n * FIN + k];
    int s0 = off[n], s1 = off[n + 1];
    for (int s = s0; s < s1; ++s)
        acc += ewgt[s] * x[(size_t)esrc[s] * FIN + k];
    xagg[(size_t)n * FIN + k] = acc;
}

// ---------------- fallback scatter path (validated round 10) ----------------

__global__ void k_selfx(const float* __restrict__ x, const float* __restrict__ dinv,
                        float* __restrict__ xagg, int N) {
    int i = blockIdx.x * 256 + threadIdx.x;
    if (i < N * (FIN / 4)) {
        int n = i >> 5;
        float s = dinv[n]; s = s * s;
        float4 v = ((const float4*)x)[i];
        v.x *= s; v.y *= s; v.z *= s; v.w *= s;
        ((float4*)xagg)[i] = v;
    }
}

__global__ __launch_bounds__(256) void k_scatx(const int* __restrict__ row,
        const int* __restrict__ col, const float* __restrict__ ew,
        const float* __restrict__ dinv, const float* __restrict__ x,
        float* __restrict__ xagg, int E) {
    int e = blockIdx.x * 8 + (threadIdx.x >> 5);
    int l = threadIdx.x & 31;
    if (e >= E) return;
    int r = row[e], c = col[e];
    float w = dinv[r] * ew[e] * dinv[c];
    const float4 v = ((const float4*)(x + (size_t)r * FIN))[l];
    float* dst = xagg + (size_t)c * FIN + l * 4;
    atomicAdd(dst + 0, w * v.x);
    atomicAdd(dst + 1, w * v.y);
    atomicAdd(dst + 2, w * v.z);
    atomicAdd(dst + 3, w * v.w);
}

extern "C" void kernel_launch(void* const* d_in, const int* in_sizes, int n_in,
                              void* d_out, int out_size, void* d_ws, size_t ws_size,
                              hipStream_t stream) {
    (void)n_in; (void)out_size;
    const float* x      = (const float*)d_in[0];
    const int*   ei     = (const int*)d_in[1];
    const float* ew     = (const float*)d_in[2];
    const int*   batch  = (const int*)d_in[3];
    const int*   labels = (const int*)d_in[4];
    const float* W1     = (const float*)d_in[5];
    const float* b1     = (const float*)d_in[6];
    const float* emb    = (const float*)d_in[7];
    const float* W2     = (const float*)d_in[8];
    const float* b2     = (const float*)d_in[9];
    const float* W3     = (const float*)d_in[10];
    const float* b3     = (const float*)d_in[11];
    const int N = in_sizes[3];   // 50000
    const int E = in_sizes[2];   // 800000
    const int* row = ei;
    const int* col = ei + E;
    const int nb = (N + 255) / 256;   // scan blocks (196 <= 256)

    // ws layout (floats/ints, 4B units)
    float* xagg   = (float*)d_ws;                   // N*128
    float* deg    = xagg + (size_t)N * FIN;         // N (becomes dinv)
    int*   cnt    = (int*)(deg + N);                // N (count, then cursor)
    int*   off    = cnt + N;                        // N+1
    int*   bsum   = off + N + 1;                    // 256
    float* pooled = (float*)(bsum + 256);           // 64*256
    int*   starts = (int*)(pooled + NGRAPH * HID);  // 65
    int*   esrc   = starts + NGRAPH + 1;            // E
    float* ewgt   = (float*)(esrc + E);             // E
    size_t need_csr = ((char*)(ewgt + E)) - ((char*)d_ws);

    k_init<<<(N + 255) / 256, 256, 0, stream>>>(deg, cnt, pooled, N);
    k_count<<<(E + 255) / 256, 256, 0, stream>>>(col, ew, deg, cnt, E);
    k_dinv<<<(N + 255) / 256, 256, 0, stream>>>(deg, N);

    if (ws_size >= need_csr) {
        // CSR pull path (atomic-free aggregation)
        k_scanA<<<nb, 256, 0, stream>>>(cnt, off, bsum, N);
        k_scanB<<<1, 256, 0, stream>>>(bsum, nb);
        k_scanC<<<nb, 256, 0, stream>>>(off, bsum, N);
        k_fill<<<(E + 255) / 256, 256, 0, stream>>>(row, col, ew, deg, off, cnt, esrc, ewgt, E);
        k_gather<<<(N + 1) / 2, 256, 0, stream>>>(off, esrc, ewgt, x, deg, xagg, N);
    } else {
        // fallback: validated atomic scatter
        k_selfx<<<(N * (FIN / 4) + 255) / 256, 256, 0, stream>>>(x, deg, xagg, N);
        k_scatx<<<(E + 7) / 8, 256, 0, stream>>>(row, col, ew, deg, x, xagg, E);
    }

    k_starts<<<1, 128, 0, stream>>>(batch, starts, N);
    k_gemmpool<<<N, 256, 0, stream>>>(xagg, W1, b1, batch, pooled, N);
    k_head<<<NGRAPH, 256, 0, stream>>>(pooled, starts, emb, labels, W2, b2, W3, b3,
                                       (float*)d_out);
}

// Round 12
// 388.096 us; speedup vs baseline: 4.4681x; 1.5772x over previous
//
#include <hip/hip_runtime.h>

#define HID 256
#define FIN 128
#define NGRAPH 64
#define NEG 0.2f

__device__ __forceinline__ float lrelu(float v) { return v >= 0.f ? v : NEG * v; }

// ---------------- setup (validated round 10/11) ----------------

__global__ void k_init(float* __restrict__ deg, int* __restrict__ cnt,
                       float* __restrict__ pooled, int N) {
    int i = blockIdx.x * 256 + threadIdx.x;
    if (i < N) { deg[i] = 1.0f; cnt[i] = 0; }
    if (i < NGRAPH * HID) pooled[i] = 0.0f;
}

__global__ void k_count(const int* __restrict__ col, const float* __restrict__ ew,
                        float* __restrict__ deg, int* __restrict__ cnt, int E) {
    int e = blockIdx.x * 256 + threadIdx.x;
    if (e < E) {
        int c = col[e];
        atomicAdd(&deg[c], ew[e]);
        atomicAdd(&cnt[c], 1);
    }
}

__global__ void k_dinv(float* __restrict__ deg, int N) {
    int i = blockIdx.x * 256 + threadIdx.x;
    if (i < N) {
        float d = deg[i];
        deg[i] = d > 0.f ? rsqrtf(d) : 0.f;
    }
}

__global__ void k_starts(const int* __restrict__ batch, int* __restrict__ starts, int N) {
    int g = threadIdx.x;
    if (g > NGRAPH) return;
    int lo = 0, hi = N;
    while (lo < hi) {
        int mid = (lo + hi) >> 1;
        if (batch[mid] < g) lo = mid + 1; else hi = mid;
    }
    starts[g] = lo;
}

// ---------------- CSR build (validated round 11) ----------------

__global__ void k_scanA(const int* __restrict__ cnt, int* __restrict__ off,
                        int* __restrict__ bsum, int N) {
    __shared__ int buf[256];
    int t = threadIdx.x, i = blockIdx.x * 256 + t;
    buf[t] = (i < N) ? cnt[i] : 0;
    __syncthreads();
    for (int s = 1; s < 256; s <<= 1) {
        int a = (t >= s) ? buf[t - s] : 0;
        __syncthreads();
        buf[t] += a;
        __syncthreads();
    }
    if (i < N) off[i + 1] = buf[t];
    if (t == 255) bsum[blockIdx.x] = buf[255];
}

__global__ void k_scanB(int* __restrict__ bsum, int nb) {
    __shared__ int buf[256];
    int t = threadIdx.x;
    buf[t] = (t < nb) ? bsum[t] : 0;
    __syncthreads();
    for (int s = 1; s < 256; s <<= 1) {
        int a = (t >= s) ? buf[t - s] : 0;
        __syncthreads();
        buf[t] += a;
        __syncthreads();
    }
    if (t < nb) bsum[t] = buf[t];
}

__global__ void k_scanC(int* __restrict__ off, const int* __restrict__ bsum, int N) {
    int i = blockIdx.x * 256 + threadIdx.x;
    if (i < N && blockIdx.x > 0) off[i + 1] += bsum[blockIdx.x - 1];
    if (i == 0) off[0] = 0;
}

__global__ void k_fill(const int* __restrict__ row, const int* __restrict__ col,
                       const float* __restrict__ ew, const float* __restrict__ dinv,
                       const int* __restrict__ off, int* __restrict__ cnt,
                       int* __restrict__ esrc, float* __restrict__ ewgt, int E) {
    int e = blockIdx.x * 256 + threadIdx.x;
    if (e >= E) return;
    int r = row[e], c = col[e];
    int p = atomicSub(&cnt[c], 1) - 1;
    int s = off[c] + p;
    esrc[s] = r;
    ewgt[s] = dinv[r] * ew[e] * dinv[c];
}

__global__ __launch_bounds__(256) void k_gather(const int* __restrict__ off,
        const int* __restrict__ esrc, const float* __restrict__ ewgt,
        const float* __restrict__ x, const float* __restrict__ dinv,
        float* __restrict__ xagg, int N) {
    int n = blockIdx.x * 2 + (threadIdx.x >> 7);
    int k = threadIdx.x & 127;
    if (n >= N) return;
    float d = dinv[n];
    float acc = d * d * x[(size_t)n * FIN + k];
    int s0 = off[n], s1 = off[n + 1];
    for (int s = s0; s < s1; ++s)
        acc += ewgt[s] * x[(size_t)esrc[s] * FIN + k];
    xagg[(size_t)n * FIN + k] = acc;
}

// ---------------- tiled fused GEMM + lrelu + pool (new this round) ----------------
// 64-row x 64-col tile per block, 256 threads, 4x4 regs/thread. LDS ~38 KB.

__global__ __launch_bounds__(256) void k_gemmpool(const float* __restrict__ xagg,
        const float* __restrict__ W1, const float* __restrict__ b1,
        const int* __restrict__ batch, float* __restrict__ pooled, int M) {
    __shared__ float xs[64][132];   // pad keeps 16B align, breaks bank stride
    __shared__ float red[16][64];
    __shared__ int   bsh[64];
    const int t = threadIdx.x;
    const int row0 = blockIdx.x * 64;
    const int col0 = blockIdx.y * 64;
    #pragma unroll
    for (int i = 0; i < 8; ++i) {
        int v = t + i * 256;
        int r = v >> 5, k4 = (v & 31) << 2;
        int rr = row0 + r; if (rr >= M) rr = M - 1;
        *(float4*)(&xs[r][k4]) = *(const float4*)(xagg + (size_t)rr * FIN + k4);
    }
    if (t < 64) {
        int rr = row0 + t; if (rr >= M) rr = M - 1;
        bsh[t] = batch[rr];
    }
    __syncthreads();
    const int tc = (t & 15) << 2;
    const int tr = (t >> 4) << 2;
    float acc[4][4] = {};
    #pragma unroll 4
    for (int k = 0; k < FIN; k += 4) {
        float4 a[4], b[4];
        #pragma unroll
        for (int i = 0; i < 4; ++i) a[i] = *(const float4*)(&xs[tr + i][k]);
        #pragma unroll
        for (int kk = 0; kk < 4; ++kk)
            b[kk] = *(const float4*)(W1 + (size_t)(k + kk) * HID + col0 + tc);
        #pragma unroll
        for (int i = 0; i < 4; ++i) {
            acc[i][0] += a[i].x * b[0].x + a[i].y * b[1].x + a[i].z * b[2].x + a[i].w * b[3].x;
            acc[i][1] += a[i].x * b[0].y + a[i].y * b[1].y + a[i].z * b[2].y + a[i].w * b[3].y;
            acc[i][2] += a[i].x * b[0].z + a[i].y * b[1].z + a[i].z * b[2].z + a[i].w * b[3].z;
            acc[i][3] += a[i].x * b[0].w + a[i].y * b[1].w + a[i].z * b[2].w + a[i].w * b[3].w;
        }
    }
    const float4 bb = *(const float4*)(b1 + col0 + tc);
    float v[4][4];
    #pragma unroll
    for (int i = 0; i < 4; ++i) {
        v[i][0] = lrelu(acc[i][0] + bb.x);
        v[i][1] = lrelu(acc[i][1] + bb.y);
        v[i][2] = lrelu(acc[i][2] + bb.z);
        v[i][3] = lrelu(acc[i][3] + bb.w);
    }
    const int g0 = bsh[0], g1 = bsh[63];
    if (g0 == g1 && row0 + 63 < M) {
        // fast path: whole tile in one graph -> block reduce, 64 atomics
        float4 s;
        s.x = v[0][0] + v[1][0] + v[2][0] + v[3][0];
        s.y = v[0][1] + v[1][1] + v[2][1] + v[3][1];
        s.z = v[0][2] + v[1][2] + v[2][2] + v[3][2];
        s.w = v[0][3] + v[1][3] + v[2][3] + v[3][3];
        *(float4*)(&red[t >> 4][tc]) = s;
        __syncthreads();
        if (t < 64) {
            float tot = 0.f;
            #pragma unroll
            for (int r = 0; r < 16; ++r) tot += red[r][t];
            atomicAdd(&pooled[g0 * HID + col0 + t], tot);
        }
    } else {
        // slow path: graph boundary or tail block
        #pragma unroll
        for (int i = 0; i < 4; ++i) {
            int r = row0 + tr + i;
            if (r < M) {
                int g = bsh[tr + i];
                atomicAdd(&pooled[g * HID + col0 + tc + 0], v[i][0]);
                atomicAdd(&pooled[g * HID + col0 + tc + 1], v[i][1]);
                atomicAdd(&pooled[g * HID + col0 + tc + 2], v[i][2]);
                atomicAdd(&pooled[g * HID + col0 + tc + 3], v[i][3]);
            }
        }
    }
}

// ---------------- head (validated round 10) ----------------

__global__ void k_head(const float* __restrict__ pooled, const int* __restrict__ starts,
                       const float* __restrict__ emb, const int* __restrict__ labels,
                       const float* __restrict__ W2, const float* __restrict__ b2,
                       const float* __restrict__ W3, const float* __restrict__ b3,
                       float* __restrict__ out) {
    __shared__ float z[384];
    __shared__ float red[256];
    int g = blockIdx.x, t = threadIdx.x;
    int cnt = starts[g + 1] - starts[g];
    float inv = 1.0f / (float)(cnt < 1 ? 1 : cnt);
    z[t] = pooled[g * HID + t] * inv;
    if (t < 128) z[HID + t] = emb[labels[g] * 128 + t];
    __syncthreads();
    float acc = b2[t];
    for (int k = 0; k < 384; ++k) acc += z[k] * W2[k * HID + t];
    red[t] = lrelu(acc) * W3[t];
    __syncthreads();
    for (int s = 128; s > 0; s >>= 1) {
        if (t < s) red[t] += red[t + s];
        __syncthreads();
    }
    if (t == 0) out[g] = red[0] + b3[0];
}

// ---------------- fallback scatter path (validated round 10) ----------------

__global__ void k_selfx(const float* __restrict__ x, const float* __restrict__ dinv,
                        float* __restrict__ xagg, int N) {
    int i = blockIdx.x * 256 + threadIdx.x;
    if (i < N * (FIN / 4)) {
        int n = i >> 5;
        float s = dinv[n]; s = s * s;
        float4 v = ((const float4*)x)[i];
        v.x *= s; v.y *= s; v.z *= s; v.w *= s;
        ((float4*)xagg)[i] = v;
    }
}

__global__ __launch_bounds__(256) void k_scatx(const int* __restrict__ row,
        const int* __restrict__ col, const float* __restrict__ ew,
        const float* __restrict__ dinv, const float* __restrict__ x,
        float* __restrict__ xagg, int E) {
    int e = blockIdx.x * 8 + (threadIdx.x >> 5);
    int l = threadIdx.x & 31;
    if (e >= E) return;
    int r = row[e], c = col[e];
    float w = dinv[r] * ew[e] * dinv[c];
    const float4 v = ((const float4*)(x + (size_t)r * FIN))[l];
    float* dst = xagg + (size_t)c * FIN + l * 4;
    atomicAdd(dst + 0, w * v.x);
    atomicAdd(dst + 1, w * v.y);
    atomicAdd(dst + 2, w * v.z);
    atomicAdd(dst + 3, w * v.w);
}

extern "C" void kernel_launch(void* const* d_in, const int* in_sizes, int n_in,
                              void* d_out, int out_size, void* d_ws, size_t ws_size,
                              hipStream_t stream) {
    (void)n_in; (void)out_size;
    const float* x      = (const float*)d_in[0];
    const int*   ei     = (const int*)d_in[1];
    const float* ew     = (const float*)d_in[2];
    const int*   batch  = (const int*)d_in[3];
    const int*   labels = (const int*)d_in[4];
    const float* W1     = (const float*)d_in[5];
    const float* b1     = (const float*)d_in[6];
    const float* emb    = (const float*)d_in[7];
    const float* W2     = (const float*)d_in[8];
    const float* b2     = (const float*)d_in[9];
    const float* W3     = (const float*)d_in[10];
    const float* b3     = (const float*)d_in[11];
    const int N = in_sizes[3];   // 50000
    const int E = in_sizes[2];   // 800000
    const int* row = ei;
    const int* col = ei + E;
    const int nb = (N + 255) / 256;

    float* xagg   = (float*)d_ws;                   // N*128
    float* deg    = xagg + (size_t)N * FIN;         // N (becomes dinv)
    int*   cnt    = (int*)(deg + N);                // N
    int*   off    = cnt + N;                        // N+1
    int*   bsum   = off + N + 1;                    // 256
    float* pooled = (float*)(bsum + 256);           // 64*256
    int*   starts = (int*)(pooled + NGRAPH * HID);  // 65
    int*   esrc   = starts + NGRAPH + 1;            // E
    float* ewgt   = (float*)(esrc + E);             // E
    size_t need_csr = ((char*)(ewgt + E)) - ((char*)d_ws);

    k_init<<<(N + 255) / 256, 256, 0, stream>>>(deg, cnt, pooled, N);
    k_count<<<(E + 255) / 256, 256, 0, stream>>>(col, ew, deg, cnt, E);
    k_dinv<<<(N + 255) / 256, 256, 0, stream>>>(deg, N);

    if (ws_size >= need_csr) {
        k_scanA<<<nb, 256, 0, stream>>>(cnt, off, bsum, N);
        k_scanB<<<1, 256, 0, stream>>>(bsum, nb);
        k_scanC<<<nb, 256, 0, stream>>>(off, bsum, N);
        k_fill<<<(E + 255) / 256, 256, 0, stream>>>(row, col, ew, deg, off, cnt, esrc, ewgt, E);
        k_gather<<<(N + 1) / 2, 256, 0, stream>>>(off, esrc, ewgt, x, deg, xagg, N);
    } else {
        k_selfx<<<(N * (FIN / 4) + 255) / 256, 256, 0, stream>>>(x, deg, xagg, N);
        k_scatx<<<(E + 7) / 8, 256, 0, stream>>>(row, col, ew, deg, x, xagg, E);
    }

    k_starts<<<1, 128, 0, stream>>>(batch, starts, N);
    dim3 ggrid((N + 63) / 64, HID / 64);
    k_gemmpool<<<ggrid, 256, 0, stream>>>(xagg, W1, b1, batch, pooled, N);
    k_head<<<NGRAPH, 256, 0, stream>>>(pooled, starts, emb, labels, W2, b2, W3, b3,
                                       (float*)d_out);
}

// Round 13
// 313.543 us; speedup vs baseline: 5.5306x; 1.2378x over previous
//
#include <hip/hip_runtime.h>

#define HID 256
#define FIN 128
#define NGRAPH 64
#define NEG 0.2f

__device__ __forceinline__ float lrelu(float v) { return v >= 0.f ? v : NEG * v; }

// ---------------- setup (validated) ----------------

__global__ void k_init(float* __restrict__ deg, int* __restrict__ cnt,
                       float* __restrict__ pooled, int N) {
    int i = blockIdx.x * 256 + threadIdx.x;
    if (i < N) { deg[i] = 1.0f; cnt[i] = 0; }
    if (i < NGRAPH * HID) pooled[i] = 0.0f;
}

__global__ void k_count(const int* __restrict__ col, const float* __restrict__ ew,
                        float* __restrict__ deg, int* __restrict__ cnt, int E) {
    int e = blockIdx.x * 256 + threadIdx.x;
    if (e < E) {
        int c = col[e];
        atomicAdd(&deg[c], ew[e]);
        atomicAdd(&cnt[c], 1);
    }
}

__global__ void k_dinv(float* __restrict__ deg, int N) {
    int i = blockIdx.x * 256 + threadIdx.x;
    if (i < N) {
        float d = deg[i];
        deg[i] = d > 0.f ? rsqrtf(d) : 0.f;
    }
}

__global__ void k_starts(const int* __restrict__ batch, int* __restrict__ starts, int N) {
    int g = threadIdx.x;
    if (g > NGRAPH) return;
    int lo = 0, hi = N;
    while (lo < hi) {
        int mid = (lo + hi) >> 1;
        if (batch[mid] < g) lo = mid + 1; else hi = mid;
    }
    starts[g] = lo;
}

// ---------------- CSR build (validated round 11) ----------------

__global__ void k_scanA(const int* __restrict__ cnt, int* __restrict__ off,
                        int* __restrict__ bsum, int N) {
    __shared__ int buf[256];
    int t = threadIdx.x, i = blockIdx.x * 256 + t;
    buf[t] = (i < N) ? cnt[i] : 0;
    __syncthreads();
    for (int s = 1; s < 256; s <<= 1) {
        int a = (t >= s) ? buf[t - s] : 0;
        __syncthreads();
        buf[t] += a;
        __syncthreads();
    }
    if (i < N) off[i + 1] = buf[t];
    if (t == 255) bsum[blockIdx.x] = buf[255];
}

__global__ void k_scanB(int* __restrict__ bsum, int nb) {
    __shared__ int buf[256];
    int t = threadIdx.x;
    buf[t] = (t < nb) ? bsum[t] : 0;
    __syncthreads();
    for (int s = 1; s < 256; s <<= 1) {
        int a = (t >= s) ? buf[t - s] : 0;
        __syncthreads();
        buf[t] += a;
        __syncthreads();
    }
    if (t < nb) bsum[t] = buf[t];
}

__global__ void k_scanC(int* __restrict__ off, const int* __restrict__ bsum, int N) {
    int i = blockIdx.x * 256 + threadIdx.x;
    if (i < N && blockIdx.x > 0) off[i + 1] += bsum[blockIdx.x - 1];
    if (i == 0) off[0] = 0;
}

__global__ void k_fill(const int* __restrict__ row, const int* __restrict__ col,
                       const float* __restrict__ ew, const float* __restrict__ dinv,
                       const int* __restrict__ off, int* __restrict__ cnt,
                       int* __restrict__ esrc, float* __restrict__ ewgt, int E) {
    int e = blockIdx.x * 256 + threadIdx.x;
    if (e >= E) return;
    int r = row[e], c = col[e];
    int p = atomicSub(&cnt[c], 1) - 1;
    int s = off[c] + p;
    esrc[s] = r;
    ewgt[s] = dinv[r] * ew[e] * dinv[c];
}

// ---------------- gather v2: float4 lanes + 2-way unroll ----------------
// 8 nodes per 256-thread block, 32 lanes/node, float4 per lane.
__global__ __launch_bounds__(256) void k_gather(const int* __restrict__ off,
        const int* __restrict__ esrc, const float* __restrict__ ewgt,
        const float* __restrict__ x, const float* __restrict__ dinv,
        float* __restrict__ xagg, int N) {
    int n = blockIdx.x * 8 + (threadIdx.x >> 5);
    int l = threadIdx.x & 31;
    if (n >= N) return;
    const float4* x4 = (const float4*)x;
    float d = dinv[n];
    float4 xv = x4[(size_t)n * 32 + l];
    float s2 = d * d;
    float ax = s2 * xv.x, ay = s2 * xv.y, az = s2 * xv.z, aw = s2 * xv.w;
    float bx = 0.f, by = 0.f, bz = 0.f, bw = 0.f;
    int s0 = off[n], s1 = off[n + 1];
    int s = s0;
    for (; s + 2 <= s1; s += 2) {
        int r0 = esrc[s], r1 = esrc[s + 1];
        float w0 = ewgt[s], w1 = ewgt[s + 1];
        float4 v0 = x4[(size_t)r0 * 32 + l];
        float4 v1 = x4[(size_t)r1 * 32 + l];
        ax += w0 * v0.x; ay += w0 * v0.y; az += w0 * v0.z; aw += w0 * v0.w;
        bx += w1 * v1.x; by += w1 * v1.y; bz += w1 * v1.z; bw += w1 * v1.w;
    }
    if (s < s1) {
        int r0 = esrc[s]; float w0 = ewgt[s];
        float4 v0 = x4[(size_t)r0 * 32 + l];
        ax += w0 * v0.x; ay += w0 * v0.y; az += w0 * v0.z; aw += w0 * v0.w;
    }
    float4 o; o.x = ax + bx; o.y = ay + by; o.z = az + bz; o.w = aw + bw;
    ((float4*)xagg)[(size_t)n * 32 + l] = o;
}

// ---------------- gemmpool v2: 64x128 tile, acc[4][8] ----------------

#define FMA8(av, p, q, ar) \
    ar[0] += (av) * (p).x; ar[1] += (av) * (p).y; ar[2] += (av) * (p).z; ar[3] += (av) * (p).w; \
    ar[4] += (av) * (q).x; ar[5] += (av) * (q).y; ar[6] += (av) * (q).z; ar[7] += (av) * (q).w;

__global__ __launch_bounds__(256) void k_gemmpool(const float* __restrict__ xagg,
        const float* __restrict__ W1, const float* __restrict__ b1,
        const int* __restrict__ batch, float* __restrict__ pooled, int M) {
    __shared__ float xs[64][132];     // 33.8 KB
    __shared__ float red[16][128];    // 8 KB
    __shared__ int   bsh[64];
    const int t = threadIdx.x;
    const int row0 = blockIdx.x * 64;
    const int col0 = blockIdx.y * 128;
    #pragma unroll
    for (int i = 0; i < 8; ++i) {
        int v = t + i * 256;
        int r = v >> 5, k4 = (v & 31) << 2;
        int rr = row0 + r; if (rr >= M) rr = M - 1;
        *(float4*)(&xs[r][k4]) = *(const float4*)(xagg + (size_t)rr * FIN + k4);
    }
    if (t < 64) {
        int rr = row0 + t; if (rr >= M) rr = M - 1;
        bsh[t] = batch[rr];
    }
    __syncthreads();
    const int tc = (t & 15) << 3;   // 8 cols
    const int tr = (t >> 4) << 2;   // 4 rows
    float acc[4][8] = {};
    for (int k = 0; k < FIN; k += 4) {
        float4 a[4], b0[4], b1v[4];
        #pragma unroll
        for (int i = 0; i < 4; ++i) a[i] = *(const float4*)(&xs[tr + i][k]);
        #pragma unroll
        for (int kk = 0; kk < 4; ++kk) {
            const float* wp = W1 + (size_t)(k + kk) * HID + col0 + tc;
            b0[kk] = *(const float4*)(wp);
            b1v[kk] = *(const float4*)(wp + 4);
        }
        #pragma unroll
        for (int i = 0; i < 4; ++i) {
            FMA8(a[i].x, b0[0], b1v[0], acc[i]);
            FMA8(a[i].y, b0[1], b1v[1], acc[i]);
            FMA8(a[i].z, b0[2], b1v[2], acc[i]);
            FMA8(a[i].w, b0[3], b1v[3], acc[i]);
        }
    }
    float bias[8];
    #pragma unroll
    for (int j = 0; j < 8; ++j) bias[j] = b1[col0 + tc + j];
    float v[4][8];
    #pragma unroll
    for (int i = 0; i < 4; ++i)
        #pragma unroll
        for (int j = 0; j < 8; ++j) v[i][j] = lrelu(acc[i][j] + bias[j]);

    const int g0 = bsh[0], g1 = bsh[63];
    if (g0 == g1 && row0 + 63 < M) {
        // fast path: whole tile one graph -> block reduce, 128 atomics
        float s[8];
        #pragma unroll
        for (int j = 0; j < 8; ++j) s[j] = v[0][j] + v[1][j] + v[2][j] + v[3][j];
        #pragma unroll
        for (int j = 0; j < 8; ++j) red[t >> 4][tc + j] = s[j];
        __syncthreads();
        if (t < 128) {
            float tot = 0.f;
            #pragma unroll
            for (int r = 0; r < 16; ++r) tot += red[r][t];
            atomicAdd(&pooled[g0 * HID + col0 + t], tot);
        }
    } else {
        #pragma unroll
        for (int i = 0; i < 4; ++i) {
            int r = row0 + tr + i;
            if (r < M) {
                int g = bsh[tr + i];
                #pragma unroll
                for (int j = 0; j < 8; ++j)
                    atomicAdd(&pooled[g * HID + col0 + tc + j], v[i][j]);
            }
        }
    }
}

// ---------------- head (validated) ----------------

__global__ void k_head(const float* __restrict__ pooled, const int* __restrict__ starts,
                       const float* __restrict__ emb, const int* __restrict__ labels,
                       const float* __restrict__ W2, const float* __restrict__ b2,
                       const float* __restrict__ W3, const float* __restrict__ b3,
                       float* __restrict__ out) {
    __shared__ float z[384];
    __shared__ float red[256];
    int g = blockIdx.x, t = threadIdx.x;
    int cnt = starts[g + 1] - starts[g];
    float inv = 1.0f / (float)(cnt < 1 ? 1 : cnt);
    z[t] = pooled[g * HID + t] * inv;
    if (t < 128) z[HID + t] = emb[labels[g] * 128 + t];
    __syncthreads();
    float acc = b2[t];
    for (int k = 0; k < 384; ++k) acc += z[k] * W2[k * HID + t];
    red[t] = lrelu(acc) * W3[t];
    __syncthreads();
    for (int s = 128; s > 0; s >>= 1) {
        if (t < s) red[t] += red[t + s];
        __syncthreads();
    }
    if (t == 0) out[g] = red[0] + b3[0];
}

// ---------------- fallback scatter path (validated round 10) ----------------

__global__ void k_selfx(const float* __restrict__ x, const float* __restrict__ dinv,
                        float* __restrict__ xagg, int N) {
    int i = blockIdx.x * 256 + threadIdx.x;
    if (i < N * (FIN / 4)) {
        int n = i >> 5;
        float s = dinv[n]; s = s * s;
        float4 v = ((const float4*)x)[i];
        v.x *= s; v.y *= s; v.z *= s; v.w *= s;
        ((float4*)xagg)[i] = v;
    }
}

__global__ __launch_bounds__(256) void k_scatx(const int* __restrict__ row,
        const int* __restrict__ col, const float* __restrict__ ew,
        const float* __restrict__ dinv, const float* __restrict__ x,
        float* __restrict__ xagg, int E) {
    int e = blockIdx.x * 8 + (threadIdx.x >> 5);
    int l = threadIdx.x & 31;
    if (e >= E) return;
    int r = row[e], c = col[e];
    float w = dinv[r] * ew[e] * dinv[c];
    const float4 v = ((const float4*)(x + (size_t)r * FIN))[l];
    float* dst = xagg + (size_t)c * FIN + l * 4;
    atomicAdd(dst + 0, w * v.x);
    atomicAdd(dst + 1, w * v.y);
    atomicAdd(dst + 2, w * v.z);
    atomicAdd(dst + 3, w * v.w);
}

extern "C" void kernel_launch(void* const* d_in, const int* in_sizes, int n_in,
                              void* d_out, int out_size, void* d_ws, size_t ws_size,
                              hipStream_t stream) {
    (void)n_in; (void)out_size;
    const float* x      = (const float*)d_in[0];
    const int*   ei     = (const int*)d_in[1];
    const float* ew     = (const float*)d_in[2];
    const int*   batch  = (const int*)d_in[3];
    const int*   labels = (const int*)d_in[4];
    const float* W1     = (const float*)d_in[5];
    const float* b1     = (const float*)d_in[6];
    const float* emb    = (const float*)d_in[7];
    const float* W2     = (const float*)d_in[8];
    const float* b2     = (const float*)d_in[9];
    const float* W3     = (const float*)d_in[10];
    const float* b3     = (const float*)d_in[11];
    const int N = in_sizes[3];   // 50000
    const int E = in_sizes[2];   // 800000
    const int* row = ei;
    const int* col = ei + E;
    const int nb = (N + 255) / 256;

    float* xagg   = (float*)d_ws;                   // N*128
    float* deg    = xagg + (size_t)N * FIN;         // N (becomes dinv)
    int*   cnt    = (int*)(deg + N);                // N
    int*   off    = cnt + N;                        // N+1
    int*   bsum   = off + N + 1;                    // 256
    float* pooled = (float*)(bsum + 256);           // 64*256
    int*   starts = (int*)(pooled + NGRAPH * HID);  // 65
    int*   esrc   = starts + NGRAPH + 1;            // E
    float* ewgt   = (float*)(esrc + E);             // E
    size_t need_csr = ((char*)(ewgt + E)) - ((char*)d_ws);

    k_init<<<(N + 255) / 256, 256, 0, stream>>>(deg, cnt, pooled, N);
    k_count<<<(E + 255) / 256, 256, 0, stream>>>(col, ew, deg, cnt, E);
    k_dinv<<<(N + 255) / 256, 256, 0, stream>>>(deg, N);

    if (ws_size >= need_csr) {
        k_scanA<<<nb, 256, 0, stream>>>(cnt, off, bsum, N);
        k_scanB<<<1, 256, 0, stream>>>(bsum, nb);
        k_scanC<<<nb, 256, 0, stream>>>(off, bsum, N);
        k_fill<<<(E + 255) / 256, 256, 0, stream>>>(row, col, ew, deg, off, cnt, esrc, ewgt, E);
        k_gather<<<(N + 7) / 8, 256, 0, stream>>>(off, esrc, ewgt, x, deg, xagg, N);
    } else {
        k_selfx<<<(N * (FIN / 4) + 255) / 256, 256, 0, stream>>>(x, deg, xagg, N);
        k_scatx<<<(E + 7) / 8, 256, 0, stream>>>(row, col, ew, deg, x, xagg, E);
    }

    k_starts<<<1, 128, 0, stream>>>(batch, starts, N);
    dim3 ggrid((N + 63) / 64, HID / 128);
    k_gemmpool<<<ggrid, 256, 0, stream>>>(xagg, W1, b1, batch, pooled, N);
    k_head<<<NGRAPH, 256, 0, stream>>>(pooled, starts, emb, labels, W2, b2, W3, b3,
                                       (float*)d_out);
}